// Round 8
// baseline (454.897 us; speedup 1.0000x reference)
//
#include <hip/hip_runtime.h>
#include <hip/hip_fp16.h>
#include <hip/hip_cooperative_groups.h>

namespace cg = cooperative_groups;

#define NN 50000
#define NE 600000
#define NG 3
#define D  128
#define NI 4096
#define BW 1024                         // nodes per bucket
#define NBUCK 49                        // ceil(NN/BW)
#define CAP 16384                       // slots per bucket (mean fill 12.3K, sigma~110)
#define REGION (NBUCK * CAP)            // 802816 slots per graph (< 2^20: rp32 packable)
#define EPT_BIN 16
#define EPB_BIN (256 * EPT_BIN)         // 4096 edges per block
#define NBLK_BIN ((NE + EPB_BIN - 1) / EPB_BIN)   // 147
#define CGRID (NBLK_BIN * NG)           // 441 blocks: bin maps 1:1; csr/fillp use first 147

typedef _Float16 half8 __attribute__((ext_vector_type(8)));
typedef float floatx4 __attribute__((ext_vector_type(4)));

static __device__ __forceinline__ float wextract(unsigned int v) {
  unsigned short u = (unsigned short)(v >> 16);
  _Float16 h;
  __builtin_memcpy(&h, &u, 2);
  return (float)h;
}

static __device__ __forceinline__ unsigned short h16(float f) {
  _Float16 h = (_Float16)f;
  unsigned short u;
  __builtin_memcpy(&u, &h, 2);
  return u;
}

// ---------------- R17: ONE cooperative kernel for the whole prep chain ----------------
// Phases: A) xcvt (grid-stride) + wcvt + cursor init; B) bin (bucket presort,
// per-wave LDS histograms, per-(block,bucket) chunk alloc from gcur cursors);
// C) csr (per-bucket degree histogram -> packed rp32 (start|deg<<20) + dinv +
// dinvh); D) fillp (scatter packed (src|fp16 dinv[src]) into bucket-local colp).
// grid.sync() between phases replaces 3 dispatch boundaries (~15-20us dead time
// each — the accounting across R4/R14/R16 shows ~120us of boundary overhead).
// R12 LESSON: never scatter 4B stores to final per-node CSR slots from an
//   unsorted stream (17x write amplification) — bucket presort gives locality.
// R13 LESSON: never do per-edge random GLOBAL atomics (cross-XCD line bouncing).
// R15 LESSON: aggb is THROUGHPUT-bound, not occupancy-bound; NT stores on a
//   buffer the next kernel reads cost more than the L2 protection buys.
// R16 LESSON: don't fuse the gather phase with MFMA behind block barriers
//   (degree stragglers + LDS-driven occupancy loss: 89us vs 58+28 split).

__global__ __launch_bounds__(256) void coop_prep_kernel(
    const float* __restrict__ x, __half* __restrict__ xh,
    const float* __restrict__ W0, const float* __restrict__ W1, const float* __restrict__ W2,
    const float* __restrict__ W3, const float* __restrict__ W4, const float* __restrict__ W5,
    __half* __restrict__ Wf, int* __restrict__ gcur,
    const int* __restrict__ e0, const int* __restrict__ e1, const int* __restrict__ e2,
    unsigned int* __restrict__ binned, unsigned int* __restrict__ rp32,
    float* __restrict__ dinv, unsigned short* __restrict__ dinvh,
    unsigned int* __restrict__ colp) {
  cg::grid_group grid = cg::this_grid();
  __shared__ int s_cnt[4][NBUCK];
  __shared__ int s_base[NBUCK];
  __shared__ int s_woff[4][NBUCK];
  __shared__ int s_arr[BW];            // deg (phase C) / cur (phase D)
  __shared__ int s_wsum[4];
  const int blk = blockIdx.x;
  const int tid = threadIdx.x;
  const int t = blk * 256 + tid;

  // ---- phase A: xcvt (grid-stride over 800000 half8 groups) ----
  for (int i = t; i < NN * D / 8; i += CGRID * 256) {
    size_t base = (size_t)i * 8;
    float4 v0 = *(const float4*)&x[base];
    float4 v1 = *(const float4*)&x[base + 4];
    half8 h;
    h[0] = (_Float16)v0.x; h[1] = (_Float16)v0.y; h[2] = (_Float16)v0.z; h[3] = (_Float16)v0.w;
    h[4] = (_Float16)v1.x; h[5] = (_Float16)v1.y; h[6] = (_Float16)v1.z; h[7] = (_Float16)v1.w;
    *(half8*)&xh[base] = h;
  }
  // ---- phase A: wcvt (first 12288 threads; MFMA-fragment weight layout) ----
  if (t < 6 * 2048) {
    const float* Wm[6] = {W0, W1, W2, W3, W4, W5};
    int mat = t >> 11;
    int fr = (t >> 6) & 31;
    int lane = t & 63;
    int tt = fr >> 2, ks = fr & 3;
    int n = tt * 16 + (lane & 15);
    int kb = ks * 32 + (lane >> 4) * 8;
    const float* W = Wm[mat];
#pragma unroll
    for (int j = 0; j < 8; j++)
      Wf[(size_t)t * 8 + j] = __float2half(W[(kb + j) * 128 + n]);
  }
  // ---- phase A: cursor init ----
  if (t < NG * NBUCK) gcur[t] = (t % NBUCK) * CAP;
  grid.sync();

  // ---- phase B: bin (all 441 blocks; g = blk/NBLK_BIN, eb = blk%NBLK_BIN) ----
  {
    int g = blk / NBLK_BIN, eb = blk % NBLK_BIN;
    const int* ei = (g == 0) ? e0 : ((g == 1) ? e1 : e2);
    int wave = tid >> 6;
    if (tid < NBUCK) { s_cnt[0][tid] = 0; s_cnt[1][tid] = 0; s_cnt[2][tid] = 0; s_cnt[3][tid] = 0; }
    __syncthreads();
    int estart = eb * EPB_BIN;
    int src[EPT_BIN], dst[EPT_BIN], rk[EPT_BIN];
#pragma unroll
    for (int i = 0; i < EPT_BIN; i++) {
      int e = estart + tid + i * 256;
      if (e < NE) {
        src[i] = ei[e];
        dst[i] = ei[NE + e];
        rk[i] = atomicAdd(&s_cnt[wave][dst[i] >> 10], 1);
      } else {
        rk[i] = -1;
      }
    }
    __syncthreads();
    if (tid < NBUCK) {
      int c0 = s_cnt[0][tid], c1 = s_cnt[1][tid], c2 = s_cnt[2][tid], c3 = s_cnt[3][tid];
      int total = c0 + c1 + c2 + c3;
      s_base[tid] = (total > 0) ? atomicAdd(&gcur[g * NBUCK + tid], total) : 0;
      s_woff[0][tid] = 0; s_woff[1][tid] = c0; s_woff[2][tid] = c0 + c1; s_woff[3][tid] = c0 + c1 + c2;
    }
    __syncthreads();
#pragma unroll
    for (int i = 0; i < EPT_BIN; i++) {
      if (rk[i] >= 0) {
        int b = dst[i] >> 10;
        int pos = s_base[b] + s_woff[wave][b] + rk[i];
        if (pos < (b + 1) * CAP)   // overflow guard (never fires: CAP=16K, mean 12.3K)
          binned[(size_t)g * REGION + pos] =
              (unsigned int)src[i] | ((unsigned int)dst[i] << 16);
      }
    }
  }
  grid.sync();

  // ---- phase C: csr (first 147 blocks; one per (graph,bucket)) ----
  if (blk < NG * NBUCK) {
    int g = blk / NBUCK, b = blk % NBUCK;
    int node0 = b * BW;
    int cbase = b * CAP;
    int total = min(gcur[g * NBUCK + b] - cbase, CAP);
    const unsigned int* bp = binned + (size_t)g * REGION + cbase;
    for (int i = tid; i < BW; i += 256) s_arr[i] = 0;
    __syncthreads();
    for (int e = tid; e < total; e += 256) {
      unsigned int p = bp[e];
      atomicAdd(&s_arr[(int)(p >> 16) - node0], 1);
    }
    __syncthreads();
    int d0 = s_arr[tid * 4], d1 = s_arr[tid * 4 + 1];
    int d2 = s_arr[tid * 4 + 2], d3 = s_arr[tid * 4 + 3];
    int s = d0 + d1 + d2 + d3;
    int lane = tid & 63;
    int incl = s;
#pragma unroll
    for (int off = 1; off < 64; off <<= 1) {
      int n = __shfl_up(incl, off, 64);
      if (lane >= off) incl += n;
    }
    if (lane == 63) s_wsum[tid >> 6] = incl;
    __syncthreads();
    int wbase = 0;
#pragma unroll
    for (int w = 0; w < 4; w++)
      if (w < (tid >> 6)) wbase += s_wsum[w];
    int ex = wbase + incl - s;
    int exs[4] = {ex, ex + d0, ex + d0 + d1, ex + d0 + d1 + d2};
    int ds[4] = {d0, d1, d2, d3};
#pragma unroll
    for (int k = 0; k < 4; k++) {
      int node = node0 + tid * 4 + k;
      if (node < NN) {
        unsigned int st = (unsigned int)(cbase + exs[k]);
        rp32[g * NN + node] = st | ((unsigned int)ds[k] << 20);
        float di = rsqrtf((float)ds[k] + 1.0f);   // deg incl. self loop
        dinv[g * NN + node] = di;
        dinvh[g * NN + node] = h16(di);
      }
    }
  }
  grid.sync();

  // ---- phase D: fillp (first 147 blocks; bucket-local scatter) ----
  if (blk < NG * NBUCK) {
    int g = blk / NBUCK, b = blk % NBUCK;
    int node0 = b * BW;
    int cbase = b * CAP;
    int total = min(gcur[g * NBUCK + b] - cbase, CAP);
    const unsigned int* bp = binned + (size_t)g * REGION + cbase;
    for (int i = tid; i < BW; i += 256) {
      int node = node0 + i;
      s_arr[i] = (node < NN) ? (int)(rp32[g * NN + node] & 0xFFFFFu) : 0;
    }
    __syncthreads();
    const unsigned short* dh = dinvh + (size_t)g * NN;
    unsigned int* cg_ = colp + (size_t)g * REGION;
    for (int e = tid; e < total; e += 256) {
      unsigned int p = bp[e];
      int srcid = (int)(p & 0xffffu);
      int r = atomicAdd(&s_arr[(int)(p >> 16) - node0], 1);
      cg_[r] = (unsigned int)srcid | ((unsigned int)dh[srcid] << 16);
    }
  }
}

// ---------------- aggregation: one wave per 4 (node, branch) rows (R14 proven) ----
// blockIdx.y = branch. 4 node-groups x 16 lanes; lane l16 owns features
// l16*8 .. +7 of its group's node. Amortizes the per-node prologue 4x, loads the
// self row once, no cross-lane reduction. Single packed rp32 load (start|deg).
// Near the random-gather throughput ceiling (~3.9 TB/s L2-miss side, FETCH
// ~181MB vs 12.8MB compulsory).

__global__ __launch_bounds__(256) void aggb_kernel(
    const __half* __restrict__ srch, const unsigned int* __restrict__ rp32,
    const unsigned int* __restrict__ colp, const float* __restrict__ dinv,
    const int* __restrict__ index, __half* __restrict__ tout, int nrows) {
  int b = blockIdx.y;
  int lane = threadIdx.x & 63;
  int grp = lane >> 4;            // node-group within wave
  int l16 = lane & 15;            // feature slot: features l16*8 .. +7
  int gb = grp << 4;              // group's lane base for shfl broadcast
  int wv = (blockIdx.x * 256 + threadIdx.x) >> 6;   // global wave id
  int w = wv * 4 + grp;           // output row this group owns
  int valid = (w < nrows);
  int wc = valid ? w : 0;
  int node = index ? index[wc] : wc;
  const _Float16* srcv = (const _Float16*)srch;
  unsigned int r32 = rp32[(size_t)b * NN + node];
  int s = (int)(r32 & 0xFFFFFu);
  int n = valid ? (int)(r32 >> 20) : 0;
  float di = dinv[b * NN + node];
  half8 selfh = *(const half8*)&srcv[(size_t)node * D + l16 * 8];
  float a[8];
#pragma unroll
  for (int k = 0; k < 8; k++) a[k] = di * (float)selfh[k];
  // wave-max degree across the 4 groups (uniform loop bound -> no divergence)
  int nmax = n;
  nmax = max(nmax, __shfl_xor(nmax, 16, 64));
  nmax = max(nmax, __shfl_xor(nmax, 32, 64));
  const unsigned int* cp = colp + (size_t)b * REGION;
  for (int j0 = 0; j0 < nmax; j0 += 16) {
    // each group loads up to 16 of its packed cols (64B coalesced per group)
    unsigned int c = (j0 + l16 < n) ? cp[s + j0 + l16] : 0u;
    int rem = nmax - j0;
    rem = (rem > 16) ? 16 : rem;
    for (int jj = 0; jj < rem; jj += 4) {
      unsigned int v0 = (unsigned int)__shfl((int)c, gb + jj + 0, 64);
      unsigned int v1 = (unsigned int)__shfl((int)c, gb + jj + 1, 64);
      unsigned int v2 = (unsigned int)__shfl((int)c, gb + jj + 2, 64);
      unsigned int v3 = (unsigned int)__shfl((int)c, gb + jj + 3, 64);
      half8 h0 = *(const half8*)&srcv[(size_t)(v0 & 0xffffu) * D + l16 * 8];
      half8 h1 = *(const half8*)&srcv[(size_t)(v1 & 0xffffu) * D + l16 * 8];
      half8 h2 = *(const half8*)&srcv[(size_t)(v2 & 0xffffu) * D + l16 * 8];
      half8 h3 = *(const half8*)&srcv[(size_t)(v3 & 0xffffu) * D + l16 * 8];
      float w0 = wextract(v0), w1 = wextract(v1);
      float w2 = wextract(v2), w3 = wextract(v3);
#pragma unroll
      for (int k = 0; k < 8; k++) a[k] = fmaf((float)h0[k], w0, a[k]);
#pragma unroll
      for (int k = 0; k < 8; k++) a[k] = fmaf((float)h1[k], w1, a[k]);
#pragma unroll
      for (int k = 0; k < 8; k++) a[k] = fmaf((float)h2[k], w2, a[k]);
#pragma unroll
      for (int k = 0; k < 8; k++) a[k] = fmaf((float)h3[k], w3, a[k]);
    }
  }
  if (valid) {
    half8 o;
#pragma unroll
    for (int k = 0; k < 8; k++) o[k] = (_Float16)(di * a[k]);
    _Float16* tv = (_Float16*)tout;
    *(half8*)&tv[(size_t)b * nrows * D + (size_t)w * D + l16 * 8] = o;
  }
}

// ---------------- fused 3-branch MFMA fp16 matmul + bias + relu + max ----------------
// A staged through LDS (coalesced global half8 loads, padded stride 136).

#define ALD 136   // padded LDS row stride (halves); 272B, 16B-aligned, conflict-light

__global__ __launch_bounds__(256) void mmf_kernel(const __half* __restrict__ A,
    const __half* __restrict__ Wf,
    const float* __restrict__ B0, const float* __restrict__ B1, const float* __restrict__ B2,
    __half* __restrict__ outh, float* __restrict__ outf, int M) {
  __shared__ _Float16 As[128 * ALD];  // 34.8 KB
  __shared__ _Float16 Ws[16384];      // 32 KB
  const float* Bb[3] = {B0, B1, B2};
  const int tid = threadIdx.x;
  const int wave = tid >> 6, lane = tid & 63;
  const int wr = (wave >> 1) * 64, wc = (wave & 1) * 64;
  const int ln = lane & 15, quad = lane >> 4;
  const int row0 = blockIdx.x * 128;
  float om[4][4][4];

  for (int b = 0; b < 3; b++) {
    const __half* Wb = Wf + (size_t)b * 16384;
#pragma unroll
    for (int i = 0; i < 8; i++) {
      int id = tid + i * 256;
      *(half8*)&Ws[id * 8] = *(const half8*)&Wb[(size_t)id * 8];
    }
    const __half* Ab = A + (size_t)b * M * D;
#pragma unroll
    for (int i = 0; i < 8; i++) {
      int idx = tid + i * 256;          // 0..2047 half8 slots
      int r = idx >> 4, c8 = idx & 15;
      int gr = row0 + r;
      gr = (gr < M) ? gr : (M - 1);
      half8 v = *(const half8*)&Ab[(size_t)gr * D + c8 * 8];
      *(half8*)&As[r * ALD + c8 * 8] = v;
    }
    __syncthreads();

    float bias[4];
#pragma unroll
    for (int ct = 0; ct < 4; ct++) bias[ct] = Bb[b][wc + ct * 16 + ln];
    floatx4 acc[4][4];
#pragma unroll
    for (int rt = 0; rt < 4; rt++)
#pragma unroll
      for (int ct = 0; ct < 4; ct++)
        acc[rt][ct] = (floatx4){bias[ct], bias[ct], bias[ct], bias[ct]};

#pragma unroll
    for (int ks = 0; ks < 4; ks++) {
      half8 av[4];
#pragma unroll
      for (int rt = 0; rt < 4; rt++)
        av[rt] = *(const half8*)&As[(wr + rt * 16 + ln) * ALD + ks * 32 + quad * 8];
#pragma unroll
      for (int ct = 0; ct < 4; ct++) {
        int tt = (wc >> 4) + ct;
        half8 bv = *(const half8*)&Ws[((tt * 4 + ks) * 64 + lane) * 8];
#pragma unroll
        for (int rt = 0; rt < 4; rt++)
          acc[rt][ct] = __builtin_amdgcn_mfma_f32_16x16x32_f16(av[rt], bv, acc[rt][ct], 0, 0, 0);
      }
    }
#pragma unroll
    for (int rt = 0; rt < 4; rt++)
#pragma unroll
      for (int ct = 0; ct < 4; ct++)
#pragma unroll
        for (int r = 0; r < 4; r++) {
          float v = fmaxf(acc[rt][ct][r], 0.f);
          om[rt][ct][r] = (b == 0) ? v : fmaxf(om[rt][ct][r], v);
        }
    __syncthreads();
  }
#pragma unroll
  for (int rt = 0; rt < 4; rt++) {
    int m = row0 + wr + rt * 16 + quad * 4;
#pragma unroll
    for (int r = 0; r < 4; r++) {
      if (m + r < M) {
#pragma unroll
        for (int ct = 0; ct < 4; ct++) {
          int n = wc + ct * 16 + ln;
          if (outh) outh[(size_t)(m + r) * D + n] = __float2half(om[rt][ct][r]);
          else      outf[(size_t)(m + r) * D + n] = om[rt][ct][r];
        }
      }
    }
  }
}

// ---------------- launch ----------------

extern "C" void kernel_launch(void* const* d_in, const int* in_sizes, int n_in,
                              void* d_out, int out_size, void* d_ws, size_t ws_size,
                              hipStream_t stream) {
  const float* x = (const float*)d_in[0];
  const int* e0 = (const int*)d_in[1];
  const int* e1 = (const int*)d_in[2];
  const int* e2 = (const int*)d_in[3];
  const int* index = (const int*)d_in[4];
  const float* w1[3] = {(const float*)d_in[5], (const float*)d_in[9],  (const float*)d_in[13]};
  const float* b1[3] = {(const float*)d_in[6], (const float*)d_in[10], (const float*)d_in[14]};
  const float* w2[3] = {(const float*)d_in[7], (const float*)d_in[11], (const float*)d_in[15]};
  const float* b2[3] = {(const float*)d_in[8], (const float*)d_in[12], (const float*)d_in[16]};
  float* out = (float*)d_out;

  char* ws = (char*)d_ws;
  size_t o = 0;
  auto alloc = [&](size_t bytes) {
    o = (o + 255) & ~(size_t)255;
    void* p = ws + o;
    o += bytes;
    return p;
  };
  unsigned int* rp32 = (unsigned int*)alloc((size_t)NG * NN * 4);
  unsigned int* colp = (unsigned int*)alloc((size_t)NG * REGION * 4);   // 9.6 MB
  float*  dinv   = (float*)alloc((size_t)NG * NN * 4);
  unsigned short* dinvh = (unsigned short*)alloc((size_t)NG * NN * 2);
  int*    gcur   = (int*)alloc((size_t)NG * NBUCK * 4);
  __half* xh     = (__half*)alloc((size_t)NN * D * 2);        // 12.8 MB
  __half* Wf     = (__half*)alloc((size_t)6 * 128 * 128 * 2); // 196 KB
  __half* t1     = (__half*)alloc((size_t)NG * NN * D * 2);   // 38.4 MB
  __half* hacc   = (__half*)alloc((size_t)NN * D * 2);        // 12.8 MB
  unsigned int* binned = (unsigned int*)t1;  // alias: consumed in coop phases C/D before aggb writes t1
  __half* t2     = t1;                       // alias: t1 free during layer 2
  (void)ws_size; (void)in_sizes; (void)n_in; (void)out_size;

  // prep chain: 4 dispatches -> 1 cooperative dispatch (3 boundaries removed)
  {
    const float* W0 = w1[0]; const float* W1 = w1[1]; const float* W2 = w1[2];
    const float* W3 = w2[0]; const float* W4 = w2[1]; const float* W5 = w2[2];
    void* cargs[] = {
        (void*)&x, (void*)&xh,
        (void*)&W0, (void*)&W1, (void*)&W2, (void*)&W3, (void*)&W4, (void*)&W5,
        (void*)&Wf, (void*)&gcur,
        (void*)&e0, (void*)&e1, (void*)&e2,
        (void*)&binned, (void*)&rp32, (void*)&dinv, (void*)&dinvh, (void*)&colp};
    hipLaunchCooperativeKernel((const void*)coop_prep_kernel,
                               dim3(CGRID), dim3(256), cargs, 0, stream);
  }

  // layer 1: t1_b = Norm_b(xh);  hacc = max_b relu(t1_b @ W1_b + b1_b)   [fp16]
  aggb_kernel<<<dim3((NN + 15) / 16, NG), 256, 0, stream>>>(
      xh, rp32, colp, dinv, nullptr, t1, NN);
  mmf_kernel<<<(NN + 127) / 128, 256, 0, stream>>>(t1, Wf, b1[0], b1[1], b1[2],
                                                   hacc, nullptr, NN);
  // layer 2: t2_b = Norm_b(hacc)[index];  out = max_b relu(t2_b @ W2_b + b2_b)
  aggb_kernel<<<dim3((NI + 15) / 16, NG), 256, 0, stream>>>(
      hacc, rp32, colp, dinv, index, t2, NI);
  mmf_kernel<<<(NI + 127) / 128, 256, 0, stream>>>(t2, Wf + (size_t)3 * 16384,
                                                   b2[0], b2[1], b2[2], nullptr, out, NI);
}

// Round 9
// 265.735 us; speedup vs baseline: 1.7118x; 1.7118x over previous
//
#include <hip/hip_runtime.h>
#include <hip/hip_fp16.h>

#define NN 50000
#define NE 600000
#define NG 3
#define D  128
#define NI 4096
#define BW 1024                         // nodes per bucket
#define NBUCK 49                        // ceil(NN/BW)
#define CAP 16384                       // slots per bucket (mean fill 12.3K, sigma~110)
#define REGION (NBUCK * CAP)            // 802816 slots per graph (< 2^20: rp32 packable)
#define EPT_BIN 16
#define EPB_BIN (256 * EPT_BIN)         // 4096 edges per block
#define NBLK_BIN ((NE + EPB_BIN - 1) / EPB_BIN)   // 147
#define PB_GRID (NBLK_BIN * NG)         // 441 blocks for prepbin
#define XCVT_TOT (NN * D / 8)           // 800000 half8 groups

typedef _Float16 half8 __attribute__((ext_vector_type(8)));
typedef float floatx4 __attribute__((ext_vector_type(4)));

static __device__ __forceinline__ unsigned short h16(float f) {
  _Float16 h = (_Float16)f;
  unsigned short u;
  __builtin_memcpy(&u, &h, 2);
  return u;
}

// ---------------- R18: prepbin = xcvt + wcvt + bucket presort, ONE kernel ----------
// gcur is zeroed by hipMemsetAsync before launch (stream-ordered); bin allocation
// is relative (b*CAP + cursor-from-0), so no init ordering hazard remains.
// R12 LESSON: never scatter 4B stores to final per-node CSR slots from an
//   unsorted stream (17x write amplification) — bucket presort gives locality.
// R13 LESSON: never do per-edge random GLOBAL atomics (cross-XCD line bouncing).
//   LDS histogram + per-bucket atomics only.
// R15 LESSON: aggb is THROUGHPUT-bound, not occupancy-bound; NT stores on a
//   buffer the next kernel reads cost more than the L2 protection buys.
// R16 LESSON: don't fuse the gather phase with MFMA behind block barriers
//   (degree stragglers + LDS occupancy loss: 89us vs 58+28 split).
// R17 LESSON: cooperative grid.sync costs ~60us per barrier at 441 blocks —
//   never use it for fine-grained phase chaining. ~17us/dispatch-boundary is
//   the real overhead; remove boundaries only via sync-free fusion.

__global__ __launch_bounds__(256) void prepbin_kernel(
    const float* __restrict__ x, __half* __restrict__ xh,
    const float* __restrict__ W0, const float* __restrict__ W1, const float* __restrict__ W2,
    const float* __restrict__ W3, const float* __restrict__ W4, const float* __restrict__ W5,
    __half* __restrict__ Wf,
    const int* __restrict__ e0, const int* __restrict__ e1, const int* __restrict__ e2,
    int* __restrict__ gcur, unsigned int* __restrict__ binned) {
  __shared__ int cnt[4][NBUCK];
  __shared__ int base[NBUCK];
  __shared__ int woff[4][NBUCK];
  const int blk = blockIdx.x;
  const int tid = threadIdx.x;
  const int t = blk * 256 + tid;

  // ---- xcvt: fp32 -> fp16 feature table (grid-stride) ----
  for (int i = t; i < XCVT_TOT; i += PB_GRID * 256) {
    size_t base8 = (size_t)i * 8;
    float4 v0 = *(const float4*)&x[base8];
    float4 v1 = *(const float4*)&x[base8 + 4];
    half8 h;
    h[0] = (_Float16)v0.x; h[1] = (_Float16)v0.y; h[2] = (_Float16)v0.z; h[3] = (_Float16)v0.w;
    h[4] = (_Float16)v1.x; h[5] = (_Float16)v1.y; h[6] = (_Float16)v1.z; h[7] = (_Float16)v1.w;
    *(half8*)&xh[base8] = h;
  }
  // ---- wcvt: 6 weight matrices -> MFMA-fragment fp16 layout (first 12288 threads) ----
  if (t < 6 * 2048) {
    const float* Wm[6] = {W0, W1, W2, W3, W4, W5};
    int mat = t >> 11;
    int fr = (t >> 6) & 31;
    int lane = t & 63;
    int tt = fr >> 2, ks = fr & 3;
    int n = tt * 16 + (lane & 15);
    int kb = ks * 32 + (lane >> 4) * 8;
    const float* W = Wm[mat];
#pragma unroll
    for (int j = 0; j < 8; j++)
      Wf[(size_t)t * 8 + j] = __float2half(W[(kb + j) * 128 + n]);
  }

  // ---- bin: per-wave LDS histograms, per-(block,bucket) chunk alloc ----
  int g = blk / NBLK_BIN, eb = blk % NBLK_BIN;
  const int* ei = (g == 0) ? e0 : ((g == 1) ? e1 : e2);
  int wave = tid >> 6;
  if (tid < NBUCK) { cnt[0][tid] = 0; cnt[1][tid] = 0; cnt[2][tid] = 0; cnt[3][tid] = 0; }
  __syncthreads();
  int estart = eb * EPB_BIN;
  int src[EPT_BIN], dst[EPT_BIN], rk[EPT_BIN];
#pragma unroll
  for (int i = 0; i < EPT_BIN; i++) {
    int e = estart + tid + i * 256;
    if (e < NE) {
      src[i] = ei[e];
      dst[i] = ei[NE + e];
      rk[i] = atomicAdd(&cnt[wave][dst[i] >> 10], 1);
    } else {
      rk[i] = -1;
    }
  }
  __syncthreads();
  if (tid < NBUCK) {
    int c0 = cnt[0][tid], c1 = cnt[1][tid], c2 = cnt[2][tid], c3 = cnt[3][tid];
    int total = c0 + c1 + c2 + c3;
    base[tid] = (total > 0) ? atomicAdd(&gcur[g * NBUCK + tid], total) : 0;
    woff[0][tid] = 0; woff[1][tid] = c0; woff[2][tid] = c0 + c1; woff[3][tid] = c0 + c1 + c2;
  }
  __syncthreads();
#pragma unroll
  for (int i = 0; i < EPT_BIN; i++) {
    if (rk[i] >= 0) {
      int b = dst[i] >> 10;
      int ofs = base[b] + woff[wave][b] + rk[i];
      if (ofs < CAP)   // overflow guard (never fires: CAP=16K, mean fill 12.3K)
        binned[(size_t)g * REGION + b * CAP + ofs] =
            (unsigned int)src[i] | ((unsigned int)dst[i] << 16);
    }
  }
}

// ---------------- R18: csrfill = csr histogram/scan + scatter, ONE kernel ----------
// Fusible because colp now stores SRC ONLY (no fp16 weight pack): the scatter
// touches nothing outside this bucket. The per-edge weight dinvh[src] moved into
// aggb as a predicated 2B gather from the 100KB L2-resident table.
__global__ __launch_bounds__(256) void csrfill_kernel(
    const unsigned int* __restrict__ binned, const int* __restrict__ gcur,
    unsigned int* __restrict__ rp32, float* __restrict__ dinv,
    unsigned short* __restrict__ dinvh, unsigned int* __restrict__ colp) {
  __shared__ int arr[BW];              // deg (pass 1) then cur (pass 2)
  __shared__ int wsum[4];
  int g = blockIdx.y, b = blockIdx.x;
  int tid = threadIdx.x;
  int node0 = b * BW;
  int cbase = b * CAP;
  int total = min(gcur[g * NBUCK + b], CAP);
  const unsigned int* bp = binned + (size_t)g * REGION + cbase;
  for (int i = tid; i < BW; i += 256) arr[i] = 0;
  __syncthreads();
  for (int e = tid; e < total; e += 256) {
    unsigned int p = bp[e];
    atomicAdd(&arr[(int)(p >> 16) - node0], 1);
  }
  __syncthreads();
  int d0 = arr[tid * 4], d1 = arr[tid * 4 + 1], d2 = arr[tid * 4 + 2], d3 = arr[tid * 4 + 3];
  int s = d0 + d1 + d2 + d3;
  int lane = tid & 63;
  int incl = s;
#pragma unroll
  for (int off = 1; off < 64; off <<= 1) {
    int n = __shfl_up(incl, off, 64);
    if (lane >= off) incl += n;
  }
  if (lane == 63) wsum[tid >> 6] = incl;
  __syncthreads();
  int wbase = 0;
#pragma unroll
  for (int w = 0; w < 4; w++)
    if (w < (tid >> 6)) wbase += wsum[w];
  int ex = wbase + incl - s;
  int exs[4] = {ex, ex + d0, ex + d0 + d1, ex + d0 + d1 + d2};
  int ds[4] = {d0, d1, d2, d3};
#pragma unroll
  for (int k = 0; k < 4; k++) {
    int node = node0 + tid * 4 + k;
    int st = cbase + exs[k];
    if (node < NN) {
      rp32[g * NN + node] = (unsigned int)st | ((unsigned int)ds[k] << 20);
      float di = rsqrtf((float)ds[k] + 1.0f);   // deg incl. self loop
      dinv[g * NN + node] = di;
      dinvh[g * NN + node] = h16(di);
    }
    arr[tid * 4 + k] = st;        // cursor init (each thread owns its own cells)
  }
  __syncthreads();
  // pass 2: scatter src into bucket-local colp slots (64KB window, line-friendly)
  unsigned int* cg = colp + (size_t)g * REGION;
  for (int e = tid; e < total; e += 256) {
    unsigned int p = bp[e];
    int r = atomicAdd(&arr[(int)(p >> 16) - node0], 1);
    cg[r] = p & 0xffffu;
  }
}

// ---------------- aggregation: one wave per 4 (node, branch) rows (R14 proven) ----
// blockIdx.y = branch. 4 node-groups x 16 lanes; lane l16 owns features
// l16*8 .. +7 of its group's node. Amortizes the per-node prologue 4x, loads the
// self row once, no cross-lane reduction. Single packed rp32 load (start|deg).
// R18: colp entries are src-only; weight = predicated gather of fp16 dinvh[src]
// (100KB L2-resident table). Predicate (edge < deg) reproduces the old
// packed-zero padding exactly (weight 0 x finite row 0 = 0).
// Near the random-gather throughput ceiling (~3.9 TB/s, FETCH ~181MB vs 12.8MB
// compulsory).

__global__ __launch_bounds__(256) void aggb_kernel(
    const __half* __restrict__ srch, const unsigned int* __restrict__ rp32,
    const unsigned int* __restrict__ colp, const float* __restrict__ dinv,
    const unsigned short* __restrict__ dinvh,
    const int* __restrict__ index, __half* __restrict__ tout, int nrows) {
  int b = blockIdx.y;
  int lane = threadIdx.x & 63;
  int grp = lane >> 4;            // node-group within wave
  int l16 = lane & 15;            // feature slot: features l16*8 .. +7
  int gb = grp << 4;              // group's lane base for shfl broadcast
  int wv = (blockIdx.x * 256 + threadIdx.x) >> 6;   // global wave id
  int w = wv * 4 + grp;           // output row this group owns
  int valid = (w < nrows);
  int wc = valid ? w : 0;
  int node = index ? index[wc] : wc;
  const _Float16* srcv = (const _Float16*)srch;
  const _Float16* dh = (const _Float16*)dinvh + (size_t)b * NN;
  unsigned int r32 = rp32[(size_t)b * NN + node];
  int s = (int)(r32 & 0xFFFFFu);
  int n = valid ? (int)(r32 >> 20) : 0;
  float di = dinv[b * NN + node];
  half8 selfh = *(const half8*)&srcv[(size_t)node * D + l16 * 8];
  float a[8];
#pragma unroll
  for (int k = 0; k < 8; k++) a[k] = di * (float)selfh[k];
  // wave-max degree across the 4 groups (uniform loop bound -> no divergence)
  int nmax = n;
  nmax = max(nmax, __shfl_xor(nmax, 16, 64));
  nmax = max(nmax, __shfl_xor(nmax, 32, 64));
  const unsigned int* cp = colp + (size_t)b * REGION;
  for (int j0 = 0; j0 < nmax; j0 += 16) {
    // each group loads up to 16 of its src ids (64B coalesced per group)
    unsigned int c = (j0 + l16 < n) ? cp[s + j0 + l16] : 0u;
    int rem = nmax - j0;
    rem = (rem > 16) ? 16 : rem;
    for (int jj = 0; jj < rem; jj += 4) {
      unsigned int v0 = (unsigned int)__shfl((int)c, gb + jj + 0, 64);
      unsigned int v1 = (unsigned int)__shfl((int)c, gb + jj + 1, 64);
      unsigned int v2 = (unsigned int)__shfl((int)c, gb + jj + 2, 64);
      unsigned int v3 = (unsigned int)__shfl((int)c, gb + jj + 3, 64);
      half8 h0 = *(const half8*)&srcv[(size_t)v0 * D + l16 * 8];
      half8 h1 = *(const half8*)&srcv[(size_t)v1 * D + l16 * 8];
      half8 h2 = *(const half8*)&srcv[(size_t)v2 * D + l16 * 8];
      half8 h3 = *(const half8*)&srcv[(size_t)v3 * D + l16 * 8];
      float w0 = (j0 + jj + 0 < n) ? (float)dh[v0] : 0.f;
      float w1 = (j0 + jj + 1 < n) ? (float)dh[v1] : 0.f;
      float w2 = (j0 + jj + 2 < n) ? (float)dh[v2] : 0.f;
      float w3 = (j0 + jj + 3 < n) ? (float)dh[v3] : 0.f;
#pragma unroll
      for (int k = 0; k < 8; k++) a[k] = fmaf((float)h0[k], w0, a[k]);
#pragma unroll
      for (int k = 0; k < 8; k++) a[k] = fmaf((float)h1[k], w1, a[k]);
#pragma unroll
      for (int k = 0; k < 8; k++) a[k] = fmaf((float)h2[k], w2, a[k]);
#pragma unroll
      for (int k = 0; k < 8; k++) a[k] = fmaf((float)h3[k], w3, a[k]);
    }
  }
  if (valid) {
    half8 o;
#pragma unroll
    for (int k = 0; k < 8; k++) o[k] = (_Float16)(di * a[k]);
    _Float16* tv = (_Float16*)tout;
    *(half8*)&tv[(size_t)b * nrows * D + (size_t)w * D + l16 * 8] = o;
  }
}

// ---------------- fused 3-branch MFMA fp16 matmul + bias + relu + max ----------------
// A staged through LDS (coalesced global half8 loads, padded stride 136).

#define ALD 136   // padded LDS row stride (halves); 272B, 16B-aligned, conflict-light

__global__ __launch_bounds__(256) void mmf_kernel(const __half* __restrict__ A,
    const __half* __restrict__ Wf,
    const float* __restrict__ B0, const float* __restrict__ B1, const float* __restrict__ B2,
    __half* __restrict__ outh, float* __restrict__ outf, int M) {
  __shared__ _Float16 As[128 * ALD];  // 34.8 KB
  __shared__ _Float16 Ws[16384];      // 32 KB
  const float* Bb[3] = {B0, B1, B2};
  const int tid = threadIdx.x;
  const int wave = tid >> 6, lane = tid & 63;
  const int wr = (wave >> 1) * 64, wc = (wave & 1) * 64;
  const int ln = lane & 15, quad = lane >> 4;
  const int row0 = blockIdx.x * 128;
  float om[4][4][4];

  for (int b = 0; b < 3; b++) {
    const __half* Wb = Wf + (size_t)b * 16384;
#pragma unroll
    for (int i = 0; i < 8; i++) {
      int id = tid + i * 256;
      *(half8*)&Ws[id * 8] = *(const half8*)&Wb[(size_t)id * 8];
    }
    const __half* Ab = A + (size_t)b * M * D;
#pragma unroll
    for (int i = 0; i < 8; i++) {
      int idx = tid + i * 256;          // 0..2047 half8 slots
      int r = idx >> 4, c8 = idx & 15;
      int gr = row0 + r;
      gr = (gr < M) ? gr : (M - 1);
      half8 v = *(const half8*)&Ab[(size_t)gr * D + c8 * 8];
      *(half8*)&As[r * ALD + c8 * 8] = v;
    }
    __syncthreads();

    float bias[4];
#pragma unroll
    for (int ct = 0; ct < 4; ct++) bias[ct] = Bb[b][wc + ct * 16 + ln];
    floatx4 acc[4][4];
#pragma unroll
    for (int rt = 0; rt < 4; rt++)
#pragma unroll
      for (int ct = 0; ct < 4; ct++)
        acc[rt][ct] = (floatx4){bias[ct], bias[ct], bias[ct], bias[ct]};

#pragma unroll
    for (int ks = 0; ks < 4; ks++) {
      half8 av[4];
#pragma unroll
      for (int rt = 0; rt < 4; rt++)
        av[rt] = *(const half8*)&As[(wr + rt * 16 + ln) * ALD + ks * 32 + quad * 8];
#pragma unroll
      for (int ct = 0; ct < 4; ct++) {
        int tt = (wc >> 4) + ct;
        half8 bv = *(const half8*)&Ws[((tt * 4 + ks) * 64 + lane) * 8];
#pragma unroll
        for (int rt = 0; rt < 4; rt++)
          acc[rt][ct] = __builtin_amdgcn_mfma_f32_16x16x32_f16(av[rt], bv, acc[rt][ct], 0, 0, 0);
      }
    }
#pragma unroll
    for (int rt = 0; rt < 4; rt++)
#pragma unroll
      for (int ct = 0; ct < 4; ct++)
#pragma unroll
        for (int r = 0; r < 4; r++) {
          float v = fmaxf(acc[rt][ct][r], 0.f);
          om[rt][ct][r] = (b == 0) ? v : fmaxf(om[rt][ct][r], v);
        }
    __syncthreads();
  }
#pragma unroll
  for (int rt = 0; rt < 4; rt++) {
    int m = row0 + wr + rt * 16 + quad * 4;
#pragma unroll
    for (int r = 0; r < 4; r++) {
      if (m + r < M) {
#pragma unroll
        for (int ct = 0; ct < 4; ct++) {
          int n = wc + ct * 16 + ln;
          if (outh) outh[(size_t)(m + r) * D + n] = __float2half(om[rt][ct][r]);
          else      outf[(size_t)(m + r) * D + n] = om[rt][ct][r];
        }
      }
    }
  }
}

// ---------------- launch ----------------

extern "C" void kernel_launch(void* const* d_in, const int* in_sizes, int n_in,
                              void* d_out, int out_size, void* d_ws, size_t ws_size,
                              hipStream_t stream) {
  const float* x = (const float*)d_in[0];
  const int* e0 = (const int*)d_in[1];
  const int* e1 = (const int*)d_in[2];
  const int* e2 = (const int*)d_in[3];
  const int* index = (const int*)d_in[4];
  const float* w1[3] = {(const float*)d_in[5], (const float*)d_in[9],  (const float*)d_in[13]};
  const float* b1[3] = {(const float*)d_in[6], (const float*)d_in[10], (const float*)d_in[14]};
  const float* w2[3] = {(const float*)d_in[7], (const float*)d_in[11], (const float*)d_in[15]};
  const float* b2[3] = {(const float*)d_in[8], (const float*)d_in[12], (const float*)d_in[16]};
  float* out = (float*)d_out;

  char* ws = (char*)d_ws;
  size_t o = 0;
  auto alloc = [&](size_t bytes) {
    o = (o + 255) & ~(size_t)255;
    void* p = ws + o;
    o += bytes;
    return p;
  };
  unsigned int* rp32 = (unsigned int*)alloc((size_t)NG * NN * 4);
  unsigned int* colp = (unsigned int*)alloc((size_t)NG * REGION * 4);   // 9.6 MB
  float*  dinv   = (float*)alloc((size_t)NG * NN * 4);
  unsigned short* dinvh = (unsigned short*)alloc((size_t)NG * NN * 2);
  int*    gcur   = (int*)alloc((size_t)NG * NBUCK * 4);
  __half* xh     = (__half*)alloc((size_t)NN * D * 2);        // 12.8 MB
  __half* Wf     = (__half*)alloc((size_t)6 * 128 * 128 * 2); // 196 KB
  __half* t1     = (__half*)alloc((size_t)NG * NN * D * 2);   // 38.4 MB
  __half* hacc   = (__half*)alloc((size_t)NN * D * 2);        // 12.8 MB
  unsigned int* binned = (unsigned int*)t1;  // alias: consumed by csrfill before aggb writes t1
  __half* t2     = t1;                       // alias: t1 free during layer 2
  (void)ws_size; (void)in_sizes; (void)n_in; (void)out_size;

  hipMemsetAsync(gcur, 0, (size_t)NG * NBUCK * 4, stream);
  prepbin_kernel<<<PB_GRID, 256, 0, stream>>>(
      x, xh, w1[0], w1[1], w1[2], w2[0], w2[1], w2[2], Wf, e0, e1, e2, gcur, binned);
  csrfill_kernel<<<dim3(NBUCK, NG), 256, 0, stream>>>(binned, gcur, rp32, dinv, dinvh, colp);

  // layer 1: t1_b = Norm_b(xh);  hacc = max_b relu(t1_b @ W1_b + b1_b)   [fp16]
  aggb_kernel<<<dim3((NN + 15) / 16, NG), 256, 0, stream>>>(
      xh, rp32, colp, dinv, dinvh, nullptr, t1, NN);
  mmf_kernel<<<(NN + 127) / 128, 256, 0, stream>>>(t1, Wf, b1[0], b1[1], b1[2],
                                                   hacc, nullptr, NN);
  // layer 2: t2_b = Norm_b(hacc)[index];  out = max_b relu(t2_b @ W2_b + b2_b)
  aggb_kernel<<<dim3((NI + 15) / 16, NG), 256, 0, stream>>>(
      hacc, rp32, colp, dinv, dinvh, index, t2, NI);
  mmf_kernel<<<(NI + 127) / 128, 256, 0, stream>>>(t2, Wf + (size_t)3 * 16384,
                                                   b2[0], b2[1], b2[2], nullptr, out, NI);
}

// Round 10
// 261.477 us; speedup vs baseline: 1.7397x; 1.0163x over previous
//
#include <hip/hip_runtime.h>
#include <hip/hip_fp16.h>

#define NN 50000
#define NE 600000
#define NG 3
#define D  128
#define NI 4096
#define BW 1024                         // nodes per bucket
#define NBUCK 49                        // ceil(NN/BW)
#define CAP 16384                       // slots per bucket (mean fill 12.3K, sigma~110)
#define REGION (NBUCK * CAP)            // 802816 slots per graph (< 2^20: rp32 packable)
#define EPT_BIN 16
#define EPB_BIN (256 * EPT_BIN)         // 4096 edges per block
#define NBLK_BIN ((NE + EPB_BIN - 1) / EPB_BIN)   // 147
#define XCVT_BLKS 3125                  // NN*D/8 threads, 8 floats each
#define WCVT_BLKS 48

typedef _Float16 half8 __attribute__((ext_vector_type(8)));
typedef float floatx4 __attribute__((ext_vector_type(4)));

static __device__ __forceinline__ float wextract(unsigned int v) {
  unsigned short u = (unsigned short)(v >> 16);
  _Float16 h;
  __builtin_memcpy(&h, &u, 2);
  return (float)h;
}

static __device__ __forceinline__ unsigned short h16(float f) {
  _Float16 h = (_Float16)f;
  unsigned short u;
  __builtin_memcpy(&u, &h, 2);
  return u;
}

// ---------------- fused prep: xcvt + wcvt + cursor init ----------------
// R14 (best verified, 262.2us): count pass + bscan eliminated via oversized
// buckets (CAP=16384); bin self-allocates chunks from gcur cursors.
// R12 LESSON: never scatter 4B stores to final per-node CSR slots from an
//   unsorted stream (17x write amplification) — bucket presort gives locality.
// R13 LESSON: never do per-edge random GLOBAL atomics (cross-XCD line bouncing).
//   LDS histogram + per-bucket atomics only.
// R15 LESSON: aggb is THROUGHPUT-bound, not occupancy-bound; NT stores on a
//   buffer the next kernel reads cost more than the L2 protection buys.
// R16 LESSON: don't fuse the gather phase with MFMA behind block barriers.
// R17 LESSON: cooperative grid.sync ~60us/barrier at 441 blocks — never.
// R18 LESSON: keep the edge weight PACKED in colp; a per-edge dinvh[src]
//   gather in aggb's inner loop costs +15% (dependent load after shfl).
//   Ordinary fusion buys only ~5-10us total — dispatch structure is optimal.

__global__ __launch_bounds__(256) void prep_kernel(
    const float* __restrict__ x, __half* __restrict__ xh,
    const float* __restrict__ W0, const float* __restrict__ W1, const float* __restrict__ W2,
    const float* __restrict__ W3, const float* __restrict__ W4, const float* __restrict__ W5,
    __half* __restrict__ Wf, int* __restrict__ gcur) {
  int blk = blockIdx.x;
  int tid = threadIdx.x;
  if (blk < XCVT_BLKS) {
    int i = blk * 256 + tid;
    size_t base = (size_t)i * 8;
    float4 v0 = *(const float4*)&x[base];
    float4 v1 = *(const float4*)&x[base + 4];
    half8 h;
    h[0] = (_Float16)v0.x; h[1] = (_Float16)v0.y; h[2] = (_Float16)v0.z; h[3] = (_Float16)v0.w;
    h[4] = (_Float16)v1.x; h[5] = (_Float16)v1.y; h[6] = (_Float16)v1.z; h[7] = (_Float16)v1.w;
    *(half8*)&xh[base] = h;
  } else if (blk < XCVT_BLKS + WCVT_BLKS) {
    const float* Wm[6] = {W0, W1, W2, W3, W4, W5};
    int t = (blk - XCVT_BLKS) * 256 + tid;     // 0 .. 6*2048-1
    int mat = t >> 11;
    int fr = (t >> 6) & 31;
    int lane = t & 63;
    int tt = fr >> 2, ks = fr & 3;
    int n = tt * 16 + (lane & 15);
    int kb = ks * 32 + (lane >> 4) * 8;
    const float* W = Wm[mat];
#pragma unroll
    for (int j = 0; j < 8; j++)
      Wf[(size_t)t * 8 + j] = __float2half(W[(kb + j) * 128 + n]);
  } else {
    // cursor init: gcur[g*NBUCK+b] = b*CAP (completes before bin_kernel launches)
    if (tid < NG * NBUCK) gcur[tid] = (tid % NBUCK) * CAP;
  }
}

// per-wave LDS histograms (cuts same-address LDS atomic serialization 4x), then
// per-(block,bucket) contiguous chunk allocation straight from global cursors.
__global__ __launch_bounds__(256) void bin_kernel(const int* __restrict__ e0,
    const int* __restrict__ e1, const int* __restrict__ e2,
    int* __restrict__ gcur, unsigned int* __restrict__ binned) {
  __shared__ int cnt[4][NBUCK];
  __shared__ int base[NBUCK];
  __shared__ int woff[4][NBUCK];
  int g = blockIdx.y;
  const int* ei = (g == 0) ? e0 : ((g == 1) ? e1 : e2);
  int tid = threadIdx.x;
  int wave = tid >> 6;
  if (tid < NBUCK) { cnt[0][tid] = 0; cnt[1][tid] = 0; cnt[2][tid] = 0; cnt[3][tid] = 0; }
  __syncthreads();
  int estart = blockIdx.x * EPB_BIN;
  int src[EPT_BIN], dst[EPT_BIN], rk[EPT_BIN];
#pragma unroll
  for (int i = 0; i < EPT_BIN; i++) {
    int e = estart + tid + i * 256;
    if (e < NE) {
      src[i] = ei[e];
      dst[i] = ei[NE + e];
      rk[i] = atomicAdd(&cnt[wave][dst[i] >> 10], 1);
    } else {
      rk[i] = -1;
    }
  }
  __syncthreads();
  if (tid < NBUCK) {
    int c0 = cnt[0][tid], c1 = cnt[1][tid], c2 = cnt[2][tid], c3 = cnt[3][tid];
    int total = c0 + c1 + c2 + c3;
    base[tid] = (total > 0) ? atomicAdd(&gcur[g * NBUCK + tid], total) : 0;
    woff[0][tid] = 0; woff[1][tid] = c0; woff[2][tid] = c0 + c1; woff[3][tid] = c0 + c1 + c2;
  }
  __syncthreads();
#pragma unroll
  for (int i = 0; i < EPT_BIN; i++) {
    if (rk[i] >= 0) {
      int b = dst[i] >> 10;
      int pos = base[b] + woff[wave][b] + rk[i];
      if (pos < (b + 1) * CAP)   // overflow guard (never fires at CAP=16K, mean 12.3K)
        binned[(size_t)g * REGION + pos] =
            (unsigned int)src[i] | ((unsigned int)dst[i] << 16);
    }
  }
}

// csr: per-bucket degree histogram from binned -> packed rp32 (start | deg<<20),
// dinv fp32 (for aggb) and dinvh fp16 (for fillp's gather).
__global__ __launch_bounds__(256) void csr_kernel(const unsigned int* __restrict__ binned,
    const int* __restrict__ gcur, unsigned int* __restrict__ rp32,
    float* __restrict__ dinv, unsigned short* __restrict__ dinvh) {
  __shared__ int deg[BW];
  __shared__ int wsum[4];
  int g = blockIdx.y, b = blockIdx.x;
  int tid = threadIdx.x;
  int node0 = b * BW;
  int cbase = b * CAP;
  int total = min(gcur[g * NBUCK + b] - cbase, CAP);
  const unsigned int* bp = binned + (size_t)g * REGION + cbase;
  for (int i = tid; i < BW; i += 256) deg[i] = 0;
  __syncthreads();
  for (int e = tid; e < total; e += 256) {
    unsigned int p = bp[e];
    atomicAdd(&deg[(int)(p >> 16) - node0], 1);
  }
  __syncthreads();
  int d0 = deg[tid * 4], d1 = deg[tid * 4 + 1], d2 = deg[tid * 4 + 2], d3 = deg[tid * 4 + 3];
  int s = d0 + d1 + d2 + d3;
  int lane = tid & 63;
  int incl = s;
#pragma unroll
  for (int off = 1; off < 64; off <<= 1) {
    int n = __shfl_up(incl, off, 64);
    if (lane >= off) incl += n;
  }
  if (lane == 63) wsum[tid >> 6] = incl;
  __syncthreads();
  int wbase = 0;
#pragma unroll
  for (int w = 0; w < 4; w++)
    if (w < (tid >> 6)) wbase += wsum[w];
  int ex = wbase + incl - s;
  int exs[4] = {ex, ex + d0, ex + d0 + d1, ex + d0 + d1 + d2};
  int ds[4] = {d0, d1, d2, d3};
#pragma unroll
  for (int k = 0; k < 4; k++) {
    int node = node0 + tid * 4 + k;
    if (node < NN) {
      unsigned int st = (unsigned int)(cbase + exs[k]);
      rp32[g * NN + node] = st | ((unsigned int)ds[k] << 20);
      float di = rsqrtf((float)ds[k] + 1.0f);   // deg incl. self loop
      dinv[g * NN + node] = di;
      dinvh[g * NN + node] = h16(di);
    }
  }
}

// fillp: scatter packed (src | fp16 dinv[src]) into bucket-local colp slots.
// Writes stay within this bucket's 64KB window -> full line utilization.
__global__ __launch_bounds__(256) void fillp_kernel(const unsigned int* __restrict__ binned,
    const int* __restrict__ gcur, const unsigned int* __restrict__ rp32,
    const unsigned short* __restrict__ dinvh, unsigned int* __restrict__ colp) {
  __shared__ int cur[BW];
  int g = blockIdx.y, b = blockIdx.x;
  int tid = threadIdx.x;
  int node0 = b * BW;
  int cbase = b * CAP;
  int total = min(gcur[g * NBUCK + b] - cbase, CAP);
  const unsigned int* bp = binned + (size_t)g * REGION + cbase;
  for (int i = tid; i < BW; i += 256) {
    int node = node0 + i;
    cur[i] = (node < NN) ? (int)(rp32[g * NN + node] & 0xFFFFFu) : 0;
  }
  __syncthreads();
  const unsigned short* dh = dinvh + (size_t)g * NN;
  unsigned int* cg = colp + (size_t)g * REGION;
  for (int e = tid; e < total; e += 256) {
    unsigned int p = bp[e];
    int srcid = (int)(p & 0xffffu);
    int r = atomicAdd(&cur[(int)(p >> 16) - node0], 1);
    cg[r] = (unsigned int)srcid | ((unsigned int)dh[srcid] << 16);
  }
}

// ---------------- aggregation: one wave per 4 (node, branch) rows ----------------
// blockIdx.y = branch. 4 node-groups x 16 lanes; lane l16 owns features
// l16*8 .. l16*8+7 of its group's node (full 128-feature row per 16-lane group).
// Amortizes the per-node prologue 4x, loads the self row once, and needs no
// cross-lane reduction. Single packed rp32 load (start|deg) removes one
// dependent gather from the prologue latency chain. AT THE random-gather
// throughput ceiling: 58us invariant under VALUBusy 55->37% and occupancy
// 65->33% (R10/R11/R15); FETCH ~181MB vs 38MB best-case-cached is the
// L2/L3-path service limit for 256B random gathers from the 12.8MB table.

__global__ __launch_bounds__(256) void aggb_kernel(
    const __half* __restrict__ srch, const unsigned int* __restrict__ rp32,
    const unsigned int* __restrict__ colp, const float* __restrict__ dinv,
    const int* __restrict__ index, __half* __restrict__ tout, int nrows) {
  int b = blockIdx.y;
  int lane = threadIdx.x & 63;
  int grp = lane >> 4;            // node-group within wave
  int l16 = lane & 15;            // feature slot: features l16*8 .. +7
  int gb = grp << 4;              // group's lane base for shfl broadcast
  int wv = (blockIdx.x * 256 + threadIdx.x) >> 6;   // global wave id
  int w = wv * 4 + grp;           // output row this group owns
  int valid = (w < nrows);
  int wc = valid ? w : 0;
  int node = index ? index[wc] : wc;
  const _Float16* srcv = (const _Float16*)srch;
  unsigned int r32 = rp32[(size_t)b * NN + node];
  int s = (int)(r32 & 0xFFFFFu);
  int n = valid ? (int)(r32 >> 20) : 0;
  float di = dinv[b * NN + node];
  half8 selfh = *(const half8*)&srcv[(size_t)node * D + l16 * 8];
  float a[8];
#pragma unroll
  for (int k = 0; k < 8; k++) a[k] = di * (float)selfh[k];
  // wave-max degree across the 4 groups (uniform loop bound -> no divergence)
  int nmax = n;
  nmax = max(nmax, __shfl_xor(nmax, 16, 64));
  nmax = max(nmax, __shfl_xor(nmax, 32, 64));
  const unsigned int* cp = colp + (size_t)b * REGION;
  for (int j0 = 0; j0 < nmax; j0 += 16) {
    // each group loads up to 16 of its packed cols (64B coalesced per group)
    unsigned int c = (j0 + l16 < n) ? cp[s + j0 + l16] : 0u;
    int rem = nmax - j0;
    rem = (rem > 16) ? 16 : rem;
    for (int jj = 0; jj < rem; jj += 4) {
      unsigned int v0 = (unsigned int)__shfl((int)c, gb + jj + 0, 64);
      unsigned int v1 = (unsigned int)__shfl((int)c, gb + jj + 1, 64);
      unsigned int v2 = (unsigned int)__shfl((int)c, gb + jj + 2, 64);
      unsigned int v3 = (unsigned int)__shfl((int)c, gb + jj + 3, 64);
      half8 h0 = *(const half8*)&srcv[(size_t)(v0 & 0xffffu) * D + l16 * 8];
      half8 h1 = *(const half8*)&srcv[(size_t)(v1 & 0xffffu) * D + l16 * 8];
      half8 h2 = *(const half8*)&srcv[(size_t)(v2 & 0xffffu) * D + l16 * 8];
      half8 h3 = *(const half8*)&srcv[(size_t)(v3 & 0xffffu) * D + l16 * 8];
      float w0 = wextract(v0), w1 = wextract(v1);
      float w2 = wextract(v2), w3 = wextract(v3);
#pragma unroll
      for (int k = 0; k < 8; k++) a[k] = fmaf((float)h0[k], w0, a[k]);
#pragma unroll
      for (int k = 0; k < 8; k++) a[k] = fmaf((float)h1[k], w1, a[k]);
#pragma unroll
      for (int k = 0; k < 8; k++) a[k] = fmaf((float)h2[k], w2, a[k]);
#pragma unroll
      for (int k = 0; k < 8; k++) a[k] = fmaf((float)h3[k], w3, a[k]);
    }
  }
  if (valid) {
    half8 o;
#pragma unroll
    for (int k = 0; k < 8; k++) o[k] = (_Float16)(di * a[k]);
    _Float16* tv = (_Float16*)tout;
    *(half8*)&tv[(size_t)b * nrows * D + (size_t)w * D + l16 * 8] = o;
  }
}

// ---------------- fused 3-branch MFMA fp16 matmul + bias + relu + max ----------------
// A staged through LDS (coalesced global half8 loads, padded stride 136).

#define ALD 136   // padded LDS row stride (halves); 272B, 16B-aligned, conflict-light

__global__ __launch_bounds__(256) void mmf_kernel(const __half* __restrict__ A,
    const __half* __restrict__ Wf,
    const float* __restrict__ B0, const float* __restrict__ B1, const float* __restrict__ B2,
    __half* __restrict__ outh, float* __restrict__ outf, int M) {
  __shared__ _Float16 As[128 * ALD];  // 34.8 KB
  __shared__ _Float16 Ws[16384];      // 32 KB
  const float* Bb[3] = {B0, B1, B2};
  const int tid = threadIdx.x;
  const int wave = tid >> 6, lane = tid & 63;
  const int wr = (wave >> 1) * 64, wc = (wave & 1) * 64;
  const int ln = lane & 15, quad = lane >> 4;
  const int row0 = blockIdx.x * 128;
  float om[4][4][4];

  for (int b = 0; b < 3; b++) {
    const __half* Wb = Wf + (size_t)b * 16384;
#pragma unroll
    for (int i = 0; i < 8; i++) {
      int id = tid + i * 256;
      *(half8*)&Ws[id * 8] = *(const half8*)&Wb[(size_t)id * 8];
    }
    const __half* Ab = A + (size_t)b * M * D;
#pragma unroll
    for (int i = 0; i < 8; i++) {
      int idx = tid + i * 256;          // 0..2047 half8 slots
      int r = idx >> 4, c8 = idx & 15;
      int gr = row0 + r;
      gr = (gr < M) ? gr : (M - 1);
      half8 v = *(const half8*)&Ab[(size_t)gr * D + c8 * 8];
      *(half8*)&As[r * ALD + c8 * 8] = v;
    }
    __syncthreads();

    float bias[4];
#pragma unroll
    for (int ct = 0; ct < 4; ct++) bias[ct] = Bb[b][wc + ct * 16 + ln];
    floatx4 acc[4][4];
#pragma unroll
    for (int rt = 0; rt < 4; rt++)
#pragma unroll
      for (int ct = 0; ct < 4; ct++)
        acc[rt][ct] = (floatx4){bias[ct], bias[ct], bias[ct], bias[ct]};

#pragma unroll
    for (int ks = 0; ks < 4; ks++) {
      half8 av[4];
#pragma unroll
      for (int rt = 0; rt < 4; rt++)
        av[rt] = *(const half8*)&As[(wr + rt * 16 + ln) * ALD + ks * 32 + quad * 8];
#pragma unroll
      for (int ct = 0; ct < 4; ct++) {
        int tt = (wc >> 4) + ct;
        half8 bv = *(const half8*)&Ws[((tt * 4 + ks) * 64 + lane) * 8];
#pragma unroll
        for (int rt = 0; rt < 4; rt++)
          acc[rt][ct] = __builtin_amdgcn_mfma_f32_16x16x32_f16(av[rt], bv, acc[rt][ct], 0, 0, 0);
      }
    }
#pragma unroll
    for (int rt = 0; rt < 4; rt++)
#pragma unroll
      for (int ct = 0; ct < 4; ct++)
#pragma unroll
        for (int r = 0; r < 4; r++) {
          float v = fmaxf(acc[rt][ct][r], 0.f);
          om[rt][ct][r] = (b == 0) ? v : fmaxf(om[rt][ct][r], v);
        }
    __syncthreads();
  }
#pragma unroll
  for (int rt = 0; rt < 4; rt++) {
    int m = row0 + wr + rt * 16 + quad * 4;
#pragma unroll
    for (int r = 0; r < 4; r++) {
      if (m + r < M) {
#pragma unroll
        for (int ct = 0; ct < 4; ct++) {
          int n = wc + ct * 16 + ln;
          if (outh) outh[(size_t)(m + r) * D + n] = __float2half(om[rt][ct][r]);
          else      outf[(size_t)(m + r) * D + n] = om[rt][ct][r];
        }
      }
    }
  }
}

// ---------------- launch ----------------

extern "C" void kernel_launch(void* const* d_in, const int* in_sizes, int n_in,
                              void* d_out, int out_size, void* d_ws, size_t ws_size,
                              hipStream_t stream) {
  const float* x = (const float*)d_in[0];
  const int* e0 = (const int*)d_in[1];
  const int* e1 = (const int*)d_in[2];
  const int* e2 = (const int*)d_in[3];
  const int* index = (const int*)d_in[4];
  const float* w1[3] = {(const float*)d_in[5], (const float*)d_in[9],  (const float*)d_in[13]};
  const float* b1[3] = {(const float*)d_in[6], (const float*)d_in[10], (const float*)d_in[14]};
  const float* w2[3] = {(const float*)d_in[7], (const float*)d_in[11], (const float*)d_in[15]};
  const float* b2[3] = {(const float*)d_in[8], (const float*)d_in[12], (const float*)d_in[16]};
  float* out = (float*)d_out;

  char* ws = (char*)d_ws;
  size_t o = 0;
  auto alloc = [&](size_t bytes) {
    o = (o + 255) & ~(size_t)255;
    void* p = ws + o;
    o += bytes;
    return p;
  };
  unsigned int* rp32 = (unsigned int*)alloc((size_t)NG * NN * 4);
  unsigned int* colp = (unsigned int*)alloc((size_t)NG * REGION * 4);   // 9.6 MB
  float*  dinv   = (float*)alloc((size_t)NG * NN * 4);
  unsigned short* dinvh = (unsigned short*)alloc((size_t)NG * NN * 2);
  int*    gcur   = (int*)alloc((size_t)NG * NBUCK * 4);
  __half* xh     = (__half*)alloc((size_t)NN * D * 2);        // 12.8 MB
  __half* Wf     = (__half*)alloc((size_t)6 * 128 * 128 * 2); // 196 KB
  __half* t1     = (__half*)alloc((size_t)NG * NN * D * 2);   // 38.4 MB
  __half* hacc   = (__half*)alloc((size_t)NN * D * 2);        // 12.8 MB
  unsigned int* binned = (unsigned int*)t1;  // alias: consumed by csr/fillp before aggb writes t1
  __half* t2     = t1;                       // alias: t1 free during layer 2
  (void)ws_size; (void)in_sizes; (void)n_in; (void)out_size;

  prep_kernel<<<XCVT_BLKS + WCVT_BLKS + 1, 256, 0, stream>>>(
      x, xh, w1[0], w1[1], w1[2], w2[0], w2[1], w2[2], Wf, gcur);
  bin_kernel<<<dim3(NBLK_BIN, NG), 256, 0, stream>>>(e0, e1, e2, gcur, binned);
  csr_kernel<<<dim3(NBUCK, NG), 256, 0, stream>>>(binned, gcur, rp32, dinv, dinvh);
  fillp_kernel<<<dim3(NBUCK, NG), 256, 0, stream>>>(binned, gcur, rp32, dinvh, colp);

  // layer 1: t1_b = Norm_b(xh);  hacc = max_b relu(t1_b @ W1_b + b1_b)   [fp16]
  aggb_kernel<<<dim3((NN + 15) / 16, NG), 256, 0, stream>>>(
      xh, rp32, colp, dinv, nullptr, t1, NN);
  mmf_kernel<<<(NN + 127) / 128, 256, 0, stream>>>(t1, Wf, b1[0], b1[1], b1[2],
                                                   hacc, nullptr, NN);
  // layer 2: t2_b = Norm_b(hacc)[index];  out = max_b relu(t2_b @ W2_b + b2_b)
  aggb_kernel<<<dim3((NI + 15) / 16, NG), 256, 0, stream>>>(
      hacc, rp32, colp, dinv, index, t2, NI);
  mmf_kernel<<<(NI + 127) / 128, 256, 0, stream>>>(t2, Wf + (size_t)3 * 16384,
                                                   b2[0], b2[1], b2[2], nullptr, out, NI);
}